// Round 5
// baseline (952.615 us; speedup 1.0000x reference)
//
#include <hip/hip_runtime.h>

// B=512, T-1=128, D=128, H=512. softmax(proj_x + shift[:,None]) == softmax(proj_x)
// => attention is timestep-invariant; only the LSTM recurrence is sequential.
//
// R5: revert to R3's PROVEN sync (bid-derived groups, MALL sc0 sc1 hand-off,
// wave0 poll + barrier). New: all-4-gate wave grid => zero cross-wave reuse of
// staged operands => h and wi tiles bypass LDS entirely:
//   - h gathered straight into MFMA A-frags (8x dwordx4 sc0 sc1, imm offsets)
//   - wi built in registers from per-lane x loads * bf16 attn frags
// LDS holds only the 33KB gate-exchange buffer (padded to 96KB for 1 block/CU).
// Counted vmcnt(8/4/0) + sched_barrier(0) pipeline x-loads -> wi MFMAs -> h MFMAs.

typedef __attribute__((ext_vector_type(8))) short short8;
typedef __attribute__((ext_vector_type(4))) float floatx4;
typedef __attribute__((ext_vector_type(4))) unsigned int uintx4;

#define NB 512
#define NT 128
#define ND 128
#define NH 512

#define GT_KH 16896            // 64*66*4 bytes per kh plane
#define LDS_BYTES 98304        // > 81920 => 1 block/CU

static __device__ __forceinline__ unsigned short f2bf(float f) {
  unsigned int u = __float_as_uint(f);
  u += 0x7fffu + ((u >> 16) & 1u);   // RNE
  return (unsigned short)(u >> 16);
}
static __device__ __forceinline__ float sigf(float x) {
  return 1.f / (1.f + __expf(-x));
}
static __device__ __forceinline__ float tanh_fast(float x) {
  const float e = __expf(-2.f * fabsf(x));
  const float r = (1.f - e) / (1.f + e);
  return copysignf(r, x);
}

// ---------------------------------------------------------------------------
// Kernel A: attn[b,d] = softmax_d( sum_t in[b,t,d]*wx[t] ); out0 = attn*in
// ---------------------------------------------------------------------------
__global__ __launch_bounds__(128) void attn_kernel(
    const float* __restrict__ in, const float* __restrict__ attn_W,
    float* __restrict__ out0, float* __restrict__ attn_ws) {
  const int b = blockIdx.x;
  const int d = threadIdx.x;
  __shared__ float wx[NT];
  __shared__ float red[4];
  wx[d] = attn_W[2 * NH + d];
  __syncthreads();
  const float* ib = in + (size_t)b * (NT * ND);
  float p = 0.f;
#pragma unroll 8
  for (int t = 0; t < NT; ++t) p = fmaf(ib[t * ND + d], wx[t], p);
  float m = p;
#pragma unroll
  for (int off = 32; off >= 1; off >>= 1) m = fmaxf(m, __shfl_xor(m, off));
  const int wv = d >> 6;
  if ((d & 63) == 0) red[wv] = m;
  __syncthreads();
  const float M = fmaxf(red[0], red[1]);
  const float e = expf(p - M);
  float s = e;
#pragma unroll
  for (int off = 32; off >= 1; off >>= 1) s += __shfl_xor(s, off);
  if ((d & 63) == 0) red[2 + wv] = s;
  __syncthreads();
  const float a = e / (red[2] + red[3]);
  attn_ws[b * ND + d] = a;
#pragma unroll 4
  for (int t = 0; t < NT; ++t)
    out0[(size_t)b * (NT * ND) + t * ND + d] = a * ib[t * ND + d];
}

// ---------------------------------------------------------------------------
// Kernel C: persistent fused LSTM recurrence. 256 blocks x 512 thr, 1/CU.
// Block (gid=bid&7, sid=bid>>3): batch rows [gid*64,+64), h-cols [sid*16,+16).
// Wave wid: rt = wid&3 (16-row tile), kh = wid>>2 (K half). Each wave computes
// all 4 gates for its rows; W frags in regs (bh[8][4], bwi[2][4]).
// ---------------------------------------------------------------------------
__global__ __launch_bounds__(512, 2) void rec_kernel(
    const float* __restrict__ in, const float* __restrict__ W_ih,
    const float* __restrict__ W_hh, const float* __restrict__ b_ih,
    const float* __restrict__ b_hh, const float* __restrict__ attn_ws,
    unsigned short* __restrict__ hbuf, unsigned int* __restrict__ flags,
    float* __restrict__ out1) {
  __shared__ __align__(16) unsigned char LDS[LDS_BYTES];
  const int tid = threadIdx.x;
  const int bid = blockIdx.x;
  const int gid = bid & 7;
  const int sid = bid >> 3;
  const int bb0 = gid * 64;
  const int n0 = sid * 16;
  const int lane = tid & 63;
  const int wid = tid >> 6;
  const int rt = wid & 3;
  const int kh = wid >> 2;
  const int colB = lane & 15;
  const int kg = lane >> 4;

  // --- W fragments -> registers (one-time) ---
  short8 bh[8][4];
  short8 bwi[2][4];
#pragma unroll
  for (int ct = 0; ct < 4; ++ct) {
    const float* wr_h = W_hh + (size_t)(ct * NH + n0 + colB) * NH + kh * 256;
    const float* wr_i = W_ih + (size_t)(ct * NH + n0 + colB) * ND + kh * 64;
#pragma unroll
    for (int ksl = 0; ksl < 8; ++ksl) {
      const int k0 = ksl * 32 + kg * 8;
      floatx4 f0 = *(const floatx4*)(wr_h + k0);
      floatx4 f1 = *(const floatx4*)(wr_h + k0 + 4);
      short8 s;
#pragma unroll
      for (int i = 0; i < 4; ++i) {
        s[i] = (short)f2bf(f0[i]);
        s[4 + i] = (short)f2bf(f1[i]);
      }
      bh[ksl][ct] = s;
    }
#pragma unroll
    for (int ksl = 0; ksl < 2; ++ksl) {
      const int k0 = ksl * 32 + kg * 8;
      floatx4 f0 = *(const floatx4*)(wr_i + k0);
      floatx4 f1 = *(const floatx4*)(wr_i + k0 + 4);
      short8 s;
#pragma unroll
      for (int i = 0; i < 4; ++i) {
        s[i] = (short)f2bf(f0[i]);
        s[4 + i] = (short)f2bf(f1[i]);
      }
      bwi[ksl][ct] = s;
    }
  }

  // --- per-lane A-row addressing ---
  const int brow = bb0 + rt * 16 + colB;     // batch row this lane's A-frags cover
  const int dbase = kh * 64 + kg * 8;        // k base within D=128 (wi)

  // --- attention frags, bf16-packed (t-invariant) ---
  unsigned int apk[2][4];
#pragma unroll
  for (int ksl = 0; ksl < 2; ++ksl) {
    const float* ap = attn_ws + (size_t)brow * ND + dbase + ksl * 32;
#pragma unroll
    for (int p = 0; p < 4; ++p)
      apk[ksl][p] = (unsigned int)f2bf(ap[2 * p]) |
                    ((unsigned int)f2bf(ap[2 * p + 1]) << 16);
  }

  // --- biases for this thread's output column ---
  const int colC = tid & 15;
  const int jC = n0 + colC;
  const int prow = tid >> 4;
  const float bi_i = b_ih[jC] + b_hh[jC];
  const float bi_f = b_ih[NH + jC] + b_hh[NH + jC];
  const float bi_g = b_ih[2 * NH + jC] + b_hh[2 * NH + jC];
  const float bi_o = b_ih[3 * NH + jC] + b_hh[3 * NH + jC];
  float creg0 = 0.f, creg1 = 0.f;

  unsigned int* fslot = flags + (gid * 32 + sid) * 16;
  const unsigned int* fpoll = flags + (gid * 32 + (lane & 31)) * 16;

  // h-gather bases (A-frag layout: lane&15 = row, lane>>4 = k-group)
  const unsigned short* hpA = hbuf + (size_t)brow * NH + kh * 256 + kg * 8;
  const unsigned short* hpB = hpA + (size_t)NB * NH;
  const float* xp = in + (size_t)brow * (NT * ND) + dbase;
  float* o1a = out1 + (size_t)(bb0 + prow) * (NT * NH) + jC;
  float* o1b = out1 + (size_t)(bb0 + 32 + prow) * (NT * NH) + jC;

  for (int t = 0; t < NT; ++t) {
    // ---- issue x loads for step t (independent of h -> overlaps poll) ----
    uintx4 xq0, xq1, xq2, xq3;
    asm volatile("global_load_dwordx4 %0, %1, off" : "=v"(xq0) : "v"(xp) : "memory");
    asm volatile("global_load_dwordx4 %0, %1, off offset:16" : "=v"(xq1) : "v"(xp) : "memory");
    asm volatile("global_load_dwordx4 %0, %1, off offset:128" : "=v"(xq2) : "v"(xp) : "memory");
    asm volatile("global_load_dwordx4 %0, %1, off offset:144" : "=v"(xq3) : "v"(xp) : "memory");

    uintx4 hq0, hq1, hq2, hq3, hq4, hq5, hq6, hq7;
    if (t > 0) {
      // ---- group sync: wave0 polls the 32 flags (MALL-coherent) ----
      if (wid == 0) {
        unsigned int v;
        do {
          asm volatile("global_load_dword %0, %1, off sc0 sc1\n\ts_waitcnt vmcnt(0)"
                       : "=v"(v) : "v"(fpoll) : "memory");
        } while (!__all((int)v >= t));
      }
      __syncthreads();                                   // (a)
      // ---- gather h A-frags straight from MALL (8 x 16B, imm offsets) ----
      const unsigned short* hp = (t & 1) ? hpB : hpA;
      asm volatile("global_load_dwordx4 %0, %1, off sc0 sc1" : "=v"(hq0) : "v"(hp) : "memory");
      asm volatile("global_load_dwordx4 %0, %1, off offset:64 sc0 sc1" : "=v"(hq1) : "v"(hp) : "memory");
      asm volatile("global_load_dwordx4 %0, %1, off offset:128 sc0 sc1" : "=v"(hq2) : "v"(hp) : "memory");
      asm volatile("global_load_dwordx4 %0, %1, off offset:192 sc0 sc1" : "=v"(hq3) : "v"(hp) : "memory");
      asm volatile("global_load_dwordx4 %0, %1, off offset:256 sc0 sc1" : "=v"(hq4) : "v"(hp) : "memory");
      asm volatile("global_load_dwordx4 %0, %1, off offset:320 sc0 sc1" : "=v"(hq5) : "v"(hp) : "memory");
      asm volatile("global_load_dwordx4 %0, %1, off offset:384 sc0 sc1" : "=v"(hq6) : "v"(hp) : "memory");
      asm volatile("global_load_dwordx4 %0, %1, off offset:448 sc0 sc1" : "=v"(hq7) : "v"(hp) : "memory");
      asm volatile("s_waitcnt vmcnt(8)" ::: "memory");   // x arrived (4 oldest)
    } else {
      asm volatile("s_waitcnt vmcnt(0)" ::: "memory");
    }
    __builtin_amdgcn_sched_barrier(0);

    floatx4 acc[4];
#pragma unroll
    for (int ct = 0; ct < 4; ++ct) acc[ct] = {0.f, 0.f, 0.f, 0.f};

    // ---- wi contribution: build A-frags in regs, 8 MFMAs ----
#pragma unroll
    for (int ksl = 0; ksl < 2; ++ksl) {
      const floatx4 x0 = __builtin_bit_cast(floatx4, ksl ? xq2 : xq0);
      const floatx4 x1 = __builtin_bit_cast(floatx4, ksl ? xq3 : xq1);
      float xv[8];
#pragma unroll
      for (int i = 0; i < 4; ++i) { xv[i] = x0[i]; xv[4 + i] = x1[i]; }
      short8 wf;
#pragma unroll
      for (int p = 0; p < 4; ++p) {
        const float a0 = __uint_as_float(apk[ksl][p] << 16);
        const float a1 = __uint_as_float(apk[ksl][p] & 0xffff0000u);
        wf[2 * p] = (short)f2bf(a0 * xv[2 * p]);
        wf[2 * p + 1] = (short)f2bf(a1 * xv[2 * p + 1]);
      }
#pragma unroll
      for (int ct = 0; ct < 4; ++ct)
        acc[ct] = __builtin_amdgcn_mfma_f32_16x16x32_bf16(wf, bwi[ksl][ct], acc[ct], 0, 0, 0);
    }
    // ---- h contribution: counted-vmcnt pipeline into 32 MFMAs ----
    if (t > 0) {
      asm volatile("s_waitcnt vmcnt(4)" ::: "memory");
      __builtin_amdgcn_sched_barrier(0);
      {
        short8 a;
        a = __builtin_bit_cast(short8, hq0);
#pragma unroll
        for (int ct = 0; ct < 4; ++ct) acc[ct] = __builtin_amdgcn_mfma_f32_16x16x32_bf16(a, bh[0][ct], acc[ct], 0, 0, 0);
        a = __builtin_bit_cast(short8, hq1);
#pragma unroll
        for (int ct = 0; ct < 4; ++ct) acc[ct] = __builtin_amdgcn_mfma_f32_16x16x32_bf16(a, bh[1][ct], acc[ct], 0, 0, 0);
        a = __builtin_bit_cast(short8, hq2);
#pragma unroll
        for (int ct = 0; ct < 4; ++ct) acc[ct] = __builtin_amdgcn_mfma_f32_16x16x32_bf16(a, bh[2][ct], acc[ct], 0, 0, 0);
        a = __builtin_bit_cast(short8, hq3);
#pragma unroll
        for (int ct = 0; ct < 4; ++ct) acc[ct] = __builtin_amdgcn_mfma_f32_16x16x32_bf16(a, bh[3][ct], acc[ct], 0, 0, 0);
      }
      asm volatile("s_waitcnt vmcnt(0)" ::: "memory");
      __builtin_amdgcn_sched_barrier(0);
      {
        short8 a;
        a = __builtin_bit_cast(short8, hq4);
#pragma unroll
        for (int ct = 0; ct < 4; ++ct) acc[ct] = __builtin_amdgcn_mfma_f32_16x16x32_bf16(a, bh[4][ct], acc[ct], 0, 0, 0);
        a = __builtin_bit_cast(short8, hq5);
#pragma unroll
        for (int ct = 0; ct < 4; ++ct) acc[ct] = __builtin_amdgcn_mfma_f32_16x16x32_bf16(a, bh[5][ct], acc[ct], 0, 0, 0);
        a = __builtin_bit_cast(short8, hq6);
#pragma unroll
        for (int ct = 0; ct < 4; ++ct) acc[ct] = __builtin_amdgcn_mfma_f32_16x16x32_bf16(a, bh[6][ct], acc[ct], 0, 0, 0);
        a = __builtin_bit_cast(short8, hq7);
#pragma unroll
        for (int ct = 0; ct < 4; ++ct) acc[ct] = __builtin_amdgcn_mfma_f32_16x16x32_bf16(a, bh[7][ct], acc[ct], 0, 0, 0);
      }
    }
    // ---- gate partials -> GT[kh][64][66] f32 (only LDS use left) ----
#pragma unroll
    for (int ct = 0; ct < 4; ++ct)
#pragma unroll
      for (int r = 0; r < 4; ++r) {
        const int row = rt * 16 + kg * 4 + r;   // C layout: row=(lane>>4)*4+reg
        *(float*)&LDS[kh * GT_KH + (row * 66 + ct * 16 + colB) * 4] = acc[ct][r];
      }
    __syncthreads();                                     // (c)
    // ---- LSTM pointwise: 2 cells/thread, sum kh partials + bias ----
    float hn0, hn1;
    {
      const float* g0 = (const float*)&LDS[(prow * 66) * 4];
      const float* g1 = (const float*)&LDS[GT_KH + (prow * 66) * 4];
      const float gi = g0[colC] + g1[colC] + bi_i;
      const float gf = g0[16 + colC] + g1[16 + colC] + bi_f;
      const float gg = g0[32 + colC] + g1[32 + colC] + bi_g;
      const float go = g0[48 + colC] + g1[48 + colC] + bi_o;
      const float cn = sigf(gf) * creg0 + sigf(gi) * tanh_fast(gg);
      hn0 = sigf(go) * tanh_fast(cn);
      creg0 = cn;
    }
    {
      const float* g0 = (const float*)&LDS[((prow + 32) * 66) * 4];
      const float* g1 = (const float*)&LDS[GT_KH + ((prow + 32) * 66) * 4];
      const float gi = g0[colC] + g1[colC] + bi_i;
      const float gf = g0[16 + colC] + g1[16 + colC] + bi_f;
      const float gg = g0[32 + colC] + g1[32 + colC] + bi_g;
      const float go = g0[48 + colC] + g1[48 + colC] + bi_o;
      const float cn = sigf(gf) * creg1 + sigf(gi) * tanh_fast(gg);
      hn1 = sigf(go) * tanh_fast(cn);
      creg1 = cn;
    }
    // ---- h hand-off: packed 4B MALL stores (lane-pair pack) ----
    const unsigned int m0 = (unsigned int)f2bf(hn0);
    const unsigned int m1 = (unsigned int)f2bf(hn1);
    const unsigned int o0 = (unsigned int)__shfl_xor((int)m0, 1);
    const unsigned int o1 = (unsigned int)__shfl_xor((int)m1, 1);
    if (!(tid & 1)) {
      unsigned short* hdst = hbuf + (size_t)((t + 1) & 1) * (NB * NH) +
                             (size_t)(bb0 + prow) * NH + jC;
      unsigned short* hdst2 = hdst + (size_t)32 * NH;
      const unsigned int d0 = m0 | (o0 << 16);
      const unsigned int d1 = m1 | (o1 << 16);
      asm volatile("global_store_dword %0, %1, off sc0 sc1" :: "v"(hdst), "v"(d0) : "memory");
      asm volatile("global_store_dword %0, %1, off sc0 sc1" :: "v"(hdst2), "v"(d1) : "memory");
    }
    // ---- off-critical-path out1 stores ----
    __builtin_nontemporal_store(hn0, o1a);
    __builtin_nontemporal_store(hn1, o1b);
    asm volatile("s_waitcnt vmcnt(0)" ::: "memory");     // h stores ACK'd at MALL
    __syncthreads();                                     // (d)
    if (tid == 0) {
      const unsigned int tv = (unsigned int)(t + 1);
      asm volatile("global_store_dword %0, %1, off sc0 sc1" :: "v"(fslot), "v"(tv) : "memory");
    }
    xp += ND;
    o1a += NH;
    o1b += NH;
  }
}

// ---------------------------------------------------------------------------
extern "C" void kernel_launch(void* const* d_in, const int* in_sizes, int n_in,
                              void* d_out, int out_size, void* d_ws, size_t ws_size,
                              hipStream_t stream) {
  (void)in_sizes; (void)n_in; (void)out_size; (void)ws_size;
  const float* in     = (const float*)d_in[0];
  const float* W_ih   = (const float*)d_in[1];
  const float* W_hh   = (const float*)d_in[2];
  const float* b_ih   = (const float*)d_in[3];
  const float* b_hh   = (const float*)d_in[4];
  const float* attn_W = (const float*)d_in[5];
  // d_in[6] (attn_b) cancels in the softmax -> unused.

  float* out0 = (float*)d_out;                          // (512,128,128)
  float* out1 = out0 + (size_t)NB * NT * ND;            // (512,128,512)

  float* attn_ws = (float*)d_ws;                                     // 256 KB
  unsigned short* hbuf = (unsigned short*)((char*)d_ws + 262144);    // 1 MB
  unsigned int* flags = (unsigned int*)((char*)d_ws + 262144 + 1048576); // 16 KB

  hipMemsetAsync(flags, 0, 16384, stream);
  attn_kernel<<<NB, 128, 0, stream>>>(in, attn_W, out0, attn_ws);
  rec_kernel<<<256, 512, 0, stream>>>(in, W_ih, W_hh, b_ih, b_hh, attn_ws,
                                      hbuf, flags, out1);
}

// Round 7
// 715.078 us; speedup vs baseline: 1.3322x; 1.3322x over previous
//
#include <hip/hip_runtime.h>

// B=512, T-1=128, D=128, H=512. softmax(proj_x + shift[:,None]) == softmax(proj_x)
// => attention is timestep-invariant; only the LSTM recurrence is sequential.
//
// R7: consolidation. Sync = R3's PROVEN protocol verbatim (bid-derived groups,
// MALL sc0 sc1 hand-off + flags, wave0 poll + __syncthreads). No XCC_ID, no
// registration, no sc0-only experiments (R4/R6 hung there).
// Compute = R5/R6 insight, refit to the 256-reg/wave budget (R5 spilled at
// ~272): bh[8][4] W_hh frags in regs (128), W_ih as LDS B-tile, h gathered
// DIRECTLY into MFMA A-frags (8x dwordx4, single burst, vmcnt(8/4/0) staging),
// x prefetched. h LDS tile + its barrier are gone; LDS/step ~100KB vs R3 240KB.

typedef __attribute__((ext_vector_type(8))) short short8;
typedef __attribute__((ext_vector_type(4))) float floatx4;
typedef __attribute__((ext_vector_type(4))) unsigned int uintx4;

#define NB 512
#define NT 128
#define ND 128
#define NH 512

#define WI_OFF 0          // W_ih slice [64][128] bf16 swizzled (16 KB)
#define GT_OFF 16384      // gates [2 kh][64][66] f32 (33792 B)
#define GT_KH  16896
#define LDS_BYTES 98304   // > 81920 => 1 block/CU

static __device__ __forceinline__ unsigned short f2bf(float f) {
  unsigned int u = __float_as_uint(f);
  u += 0x7fffu + ((u >> 16) & 1u);   // RNE
  return (unsigned short)(u >> 16);
}
static __device__ __forceinline__ float sigf(float x) {
  return 1.f / (1.f + __expf(-x));
}
static __device__ __forceinline__ float tanh_fast(float x) {
  const float e = __expf(-2.f * fabsf(x));
  const float r = (1.f - e) / (1.f + e);
  return copysignf(r, x);
}

// ---------------------------------------------------------------------------
// Kernel A: attn[b,d] = softmax_d( sum_t in[b,t,d]*wx[t] ); out0 = attn*in
// ---------------------------------------------------------------------------
__global__ __launch_bounds__(128) void attn_kernel(
    const float* __restrict__ in, const float* __restrict__ attn_W,
    float* __restrict__ out0, float* __restrict__ attn_ws) {
  const int b = blockIdx.x;
  const int d = threadIdx.x;
  __shared__ float wx[NT];
  __shared__ float red[4];
  wx[d] = attn_W[2 * NH + d];
  __syncthreads();
  const float* ib = in + (size_t)b * (NT * ND);
  float p = 0.f;
#pragma unroll 8
  for (int t = 0; t < NT; ++t) p = fmaf(ib[t * ND + d], wx[t], p);
  float m = p;
#pragma unroll
  for (int off = 32; off >= 1; off >>= 1) m = fmaxf(m, __shfl_xor(m, off));
  const int wv = d >> 6;
  if ((d & 63) == 0) red[wv] = m;
  __syncthreads();
  const float M = fmaxf(red[0], red[1]);
  const float e = expf(p - M);
  float s = e;
#pragma unroll
  for (int off = 32; off >= 1; off >>= 1) s += __shfl_xor(s, off);
  if ((d & 63) == 0) red[2 + wv] = s;
  __syncthreads();
  const float a = e / (red[2] + red[3]);
  attn_ws[b * ND + d] = a;
#pragma unroll 4
  for (int t = 0; t < NT; ++t)
    out0[(size_t)b * (NT * ND) + t * ND + d] = a * ib[t * ND + d];
}

// ---------------------------------------------------------------------------
// Kernel C: persistent fused LSTM recurrence. 256 blocks x 512 thr, 1/CU.
// Block (gid=bid&7, sid=bid>>3): batch rows [gid*64,+64), h-cols [sid*16,+16).
// Wave wid: rt = wid&3 (16-row tile), kh = wid>>2 (K half). Each wave computes
// all 4 gates for its rows; bh[8][4] in regs, W_ih B-frags from LDS tile.
// ---------------------------------------------------------------------------
__global__ __launch_bounds__(512, 2) void rec_kernel(
    const float* __restrict__ in, const float* __restrict__ W_ih,
    const float* __restrict__ W_hh, const float* __restrict__ b_ih,
    const float* __restrict__ b_hh, const float* __restrict__ attn_ws,
    unsigned short* __restrict__ hbuf, unsigned int* __restrict__ flags,
    float* __restrict__ out1) {
  __shared__ __align__(16) unsigned char LDS[LDS_BYTES];
  const int tid = threadIdx.x;
  const int bid = blockIdx.x;
  const int gid = bid & 7;
  const int sid = bid >> 3;
  const int bb0 = gid * 64;
  const int n0 = sid * 16;
  const int lane = tid & 63;
  const int wid = tid >> 6;
  const int rt = wid & 3;
  const int kh = wid >> 2;
  const int colB = lane & 15;
  const int kg = lane >> 4;

  // ---- W_hh fragments -> registers (one-time, 128 regs) ----
  short8 bh[8][4];
#pragma unroll
  for (int ct = 0; ct < 4; ++ct) {
    const float* wr_h = W_hh + (size_t)(ct * NH + n0 + colB) * NH + kh * 256;
#pragma unroll
    for (int ksl = 0; ksl < 8; ++ksl) {
      const int k0 = ksl * 32 + kg * 8;
      floatx4 f0 = *(const floatx4*)(wr_h + k0);
      floatx4 f1 = *(const floatx4*)(wr_h + k0 + 4);
      short8 s;
#pragma unroll
      for (int i = 0; i < 4; ++i) {
        s[i] = (short)f2bf(f0[i]);
        s[4 + i] = (short)f2bf(f1[i]);
      }
      bh[ksl][ct] = s;
    }
  }
  // ---- W_ih slice -> LDS tile [64][128] bf16, swizzled ----
#pragma unroll 4
  for (int it = 0; it < 16; ++it) {
    const int jj = it * 4 + (tid >> 7);            // 0..63 = gate*16 + col
    const int k = tid & 127;
    const int j = (jj >> 4) * NH + n0 + (jj & 15);
    *(unsigned short*)&LDS[WI_OFF + jj * 256 + ((2 * k) ^ ((jj & 7) << 4))] =
        f2bf(W_ih[j * ND + k]);
  }

  // ---- per-lane A-side addressing ----
  const int brow = bb0 + rt * 16 + colB;    // A row (lane&15 = row)
  const int dbase = kh * 64 + kg * 8;       // k base within D (lane>>4 = kgrp)

  // ---- attention frags, bf16-packed (t-invariant) ----
  unsigned int apk[2][4];
#pragma unroll
  for (int ksl = 0; ksl < 2; ++ksl) {
    const float* ap = attn_ws + (size_t)brow * ND + dbase + ksl * 32;
#pragma unroll
    for (int p = 0; p < 4; ++p)
      apk[ksl][p] = (unsigned int)f2bf(ap[2 * p]) |
                    ((unsigned int)f2bf(ap[2 * p + 1]) << 16);
  }

  // ---- biases ----
  const int colC = tid & 15;
  const int jC = n0 + colC;
  const int prow = tid >> 4;
  const float bi_i = b_ih[jC] + b_hh[jC];
  const float bi_f = b_ih[NH + jC] + b_hh[NH + jC];
  const float bi_g = b_ih[2 * NH + jC] + b_hh[2 * NH + jC];
  const float bi_o = b_ih[3 * NH + jC] + b_hh[3 * NH + jC];
  float creg0 = 0.f, creg1 = 0.f;

  unsigned int* fslot = flags + (gid * 32 + sid) * 16;
  const unsigned int* fpoll = flags + (gid * 32 + (lane & 31)) * 16;

  const unsigned short* hpbase = hbuf + (size_t)brow * NH + kh * 256 + kg * 8;
  const float* xp0 = in + (size_t)brow * (NT * ND) + dbase;
  float* o1a = out1 + (size_t)(bb0 + prow) * (NT * NH) + jC;
  float* o1b = out1 + (size_t)(bb0 + 32 + prow) * (NT * NH) + jC;

  // ---- prologue: issue x_0 loads; finish WI staging ----
  uintx4 xq0, xq1, xq2, xq3;
  asm volatile("global_load_dwordx4 %0, %1, off" : "=v"(xq0) : "v"(xp0) : "memory");
  asm volatile("global_load_dwordx4 %0, %1, off offset:16" : "=v"(xq1) : "v"(xp0) : "memory");
  asm volatile("global_load_dwordx4 %0, %1, off offset:128" : "=v"(xq2) : "v"(xp0) : "memory");
  asm volatile("global_load_dwordx4 %0, %1, off offset:144" : "=v"(xq3) : "v"(xp0) : "memory");
  __syncthreads();

  for (int t = 0; t < NT; ++t) {
    floatx4 acc[4];
#pragma unroll
    for (int ct = 0; ct < 4; ++ct) acc[ct] = {0.f, 0.f, 0.f, 0.f};

    uintx4 hq0, hq1, hq2, hq3, hq4, hq5, hq6, hq7;
    const unsigned short* hp = hpbase + ((t & 1) ? (size_t)(NB * NH) : 0);

    if (t > 0) {
      // ---- group sync: wave0 polls the 32 flags (MALL-coherent) ----
      if (wid == 0) {
        unsigned int v;
        do {
          asm volatile("global_load_dword %0, %1, off sc0 sc1\n\ts_waitcnt vmcnt(0)"
                       : "=v"(v) : "v"(fpoll) : "memory");
        } while (!__all((int)v >= t));
      }
      __syncthreads();                                   // (a)
      // ---- h gather: 8x16B burst straight into A-frags ----
      asm volatile("global_load_dwordx4 %0, %1, off sc0 sc1" : "=v"(hq0) : "v"(hp) : "memory");
      asm volatile("global_load_dwordx4 %0, %1, off offset:64 sc0 sc1" : "=v"(hq1) : "v"(hp) : "memory");
      asm volatile("global_load_dwordx4 %0, %1, off offset:128 sc0 sc1" : "=v"(hq2) : "v"(hp) : "memory");
      asm volatile("global_load_dwordx4 %0, %1, off offset:192 sc0 sc1" : "=v"(hq3) : "v"(hp) : "memory");
      asm volatile("global_load_dwordx4 %0, %1, off offset:256 sc0 sc1" : "=v"(hq4) : "v"(hp) : "memory");
      asm volatile("global_load_dwordx4 %0, %1, off offset:320 sc0 sc1" : "=v"(hq5) : "v"(hp) : "memory");
      asm volatile("global_load_dwordx4 %0, %1, off offset:384 sc0 sc1" : "=v"(hq6) : "v"(hp) : "memory");
      asm volatile("global_load_dwordx4 %0, %1, off offset:448 sc0 sc1" : "=v"(hq7) : "v"(hp) : "memory");
      asm volatile("s_waitcnt vmcnt(8)" ::: "memory");   // x (and out1) drained
    } else {
      asm volatile("s_waitcnt vmcnt(0)" ::: "memory");
    }
    __builtin_amdgcn_sched_barrier(0);

    // ---- wi contribution: wf in regs, W_ih B-frags from LDS, 8 MFMAs ----
#pragma unroll
    for (int ksl = 0; ksl < 2; ++ksl) {
      const int k2 = kh * 128 + ksl * 64 + kg * 16;
      const int sw = (colB & 7) << 4;
      short8 b0 = *(const short8*)&LDS[WI_OFF + (0 * 16 + colB) * 256 + (k2 ^ sw)];
      short8 b1 = *(const short8*)&LDS[WI_OFF + (1 * 16 + colB) * 256 + (k2 ^ sw)];
      short8 b2 = *(const short8*)&LDS[WI_OFF + (2 * 16 + colB) * 256 + (k2 ^ sw)];
      short8 b3 = *(const short8*)&LDS[WI_OFF + (3 * 16 + colB) * 256 + (k2 ^ sw)];
      const floatx4 x0 = __builtin_bit_cast(floatx4, ksl ? xq2 : xq0);
      const floatx4 x1 = __builtin_bit_cast(floatx4, ksl ? xq3 : xq1);
      float xv[8];
#pragma unroll
      for (int i = 0; i < 4; ++i) { xv[i] = x0[i]; xv[4 + i] = x1[i]; }
      short8 wf;
#pragma unroll
      for (int p = 0; p < 4; ++p) {
        const float a0 = __uint_as_float(apk[ksl][p] << 16);
        const float a1 = __uint_as_float(apk[ksl][p] & 0xffff0000u);
        wf[2 * p] = (short)f2bf(a0 * xv[2 * p]);
        wf[2 * p + 1] = (short)f2bf(a1 * xv[2 * p + 1]);
      }
      acc[0] = __builtin_amdgcn_mfma_f32_16x16x32_bf16(wf, b0, acc[0], 0, 0, 0);
      acc[1] = __builtin_amdgcn_mfma_f32_16x16x32_bf16(wf, b1, acc[1], 0, 0, 0);
      acc[2] = __builtin_amdgcn_mfma_f32_16x16x32_bf16(wf, b2, acc[2], 0, 0, 0);
      acc[3] = __builtin_amdgcn_mfma_f32_16x16x32_bf16(wf, b3, acc[3], 0, 0, 0);
    }
    // ---- h contribution: staged consumption, 32 MFMAs ----
    if (t > 0) {
      asm volatile("s_waitcnt vmcnt(4)" ::: "memory");   // hq0..3 ready
      __builtin_amdgcn_sched_barrier(0);
      {
        short8 a;
        a = __builtin_bit_cast(short8, hq0);
#pragma unroll
        for (int ct = 0; ct < 4; ++ct) acc[ct] = __builtin_amdgcn_mfma_f32_16x16x32_bf16(a, bh[0][ct], acc[ct], 0, 0, 0);
        a = __builtin_bit_cast(short8, hq1);
#pragma unroll
        for (int ct = 0; ct < 4; ++ct) acc[ct] = __builtin_amdgcn_mfma_f32_16x16x32_bf16(a, bh[1][ct], acc[ct], 0, 0, 0);
        a = __builtin_bit_cast(short8, hq2);
#pragma unroll
        for (int ct = 0; ct < 4; ++ct) acc[ct] = __builtin_amdgcn_mfma_f32_16x16x32_bf16(a, bh[2][ct], acc[ct], 0, 0, 0);
        a = __builtin_bit_cast(short8, hq3);
#pragma unroll
        for (int ct = 0; ct < 4; ++ct) acc[ct] = __builtin_amdgcn_mfma_f32_16x16x32_bf16(a, bh[3][ct], acc[ct], 0, 0, 0);
      }
      asm volatile("s_waitcnt vmcnt(0)" ::: "memory");   // hq4..7 ready
      __builtin_amdgcn_sched_barrier(0);
      {
        short8 a;
        a = __builtin_bit_cast(short8, hq4);
#pragma unroll
        for (int ct = 0; ct < 4; ++ct) acc[ct] = __builtin_amdgcn_mfma_f32_16x16x32_bf16(a, bh[4][ct], acc[ct], 0, 0, 0);
        a = __builtin_bit_cast(short8, hq5);
#pragma unroll
        for (int ct = 0; ct < 4; ++ct) acc[ct] = __builtin_amdgcn_mfma_f32_16x16x32_bf16(a, bh[5][ct], acc[ct], 0, 0, 0);
        a = __builtin_bit_cast(short8, hq6);
#pragma unroll
        for (int ct = 0; ct < 4; ++ct) acc[ct] = __builtin_amdgcn_mfma_f32_16x16x32_bf16(a, bh[6][ct], acc[ct], 0, 0, 0);
        a = __builtin_bit_cast(short8, hq7);
#pragma unroll
        for (int ct = 0; ct < 4; ++ct) acc[ct] = __builtin_amdgcn_mfma_f32_16x16x32_bf16(a, bh[7][ct], acc[ct], 0, 0, 0);
      }
    }
    // ---- gate partials -> GT[kh][64][66] f32 ----
#pragma unroll
    for (int ct = 0; ct < 4; ++ct)
#pragma unroll
      for (int r = 0; r < 4; ++r) {
        const int row = rt * 16 + kg * 4 + r;   // C layout: row=(lane>>4)*4+reg
        *(float*)&LDS[GT_OFF + kh * GT_KH + (row * 66 + ct * 16 + colB) * 4] = acc[ct][r];
      }
    __syncthreads();                                     // (c)
    // ---- LSTM pointwise: 2 cells/thread ----
    float hn0, hn1;
    {
      const float* g0 = (const float*)&LDS[GT_OFF + (prow * 66) * 4];
      const float* g1 = (const float*)&LDS[GT_OFF + GT_KH + (prow * 66) * 4];
      const float gi = g0[colC] + g1[colC] + bi_i;
      const float gf = g0[16 + colC] + g1[16 + colC] + bi_f;
      const float gg = g0[32 + colC] + g1[32 + colC] + bi_g;
      const float go = g0[48 + colC] + g1[48 + colC] + bi_o;
      const float cn = sigf(gf) * creg0 + sigf(gi) * tanh_fast(gg);
      hn0 = sigf(go) * tanh_fast(cn);
      creg0 = cn;
    }
    {
      const float* g0 = (const float*)&LDS[GT_OFF + ((prow + 32) * 66) * 4];
      const float* g1 = (const float*)&LDS[GT_OFF + GT_KH + ((prow + 32) * 66) * 4];
      const float gi = g0[colC] + g1[colC] + bi_i;
      const float gf = g0[16 + colC] + g1[16 + colC] + bi_f;
      const float gg = g0[32 + colC] + g1[32 + colC] + bi_g;
      const float go = g0[48 + colC] + g1[48 + colC] + bi_o;
      const float cn = sigf(gf) * creg1 + sigf(gi) * tanh_fast(gg);
      hn1 = sigf(go) * tanh_fast(cn);
      creg1 = cn;
    }
    // ---- h hand-off: packed 4B MALL stores (lane-pair pack) ----
    const unsigned int m0 = (unsigned int)f2bf(hn0);
    const unsigned int m1 = (unsigned int)f2bf(hn1);
    const unsigned int o0 = (unsigned int)__shfl_xor((int)m0, 1);
    const unsigned int o1 = (unsigned int)__shfl_xor((int)m1, 1);
    if (!(tid & 1)) {
      unsigned short* hdst = hbuf + (size_t)((t + 1) & 1) * (NB * NH) +
                             (size_t)(bb0 + prow) * NH + jC;
      unsigned short* hdst2 = hdst + (size_t)32 * NH;
      const unsigned int d0 = m0 | (o0 << 16);
      const unsigned int d1 = m1 | (o1 << 16);
      asm volatile("global_store_dword %0, %1, off sc0 sc1" :: "v"(hdst), "v"(d0) : "memory");
      asm volatile("global_store_dword %0, %1, off sc0 sc1" :: "v"(hdst2), "v"(d1) : "memory");
    }
    asm volatile("s_waitcnt vmcnt(0)" ::: "memory");     // h stores ACK'd at MALL
    __syncthreads();                                     // (d)
    if (tid == 0) {
      const unsigned int tv = (unsigned int)(t + 1);
      asm volatile("global_store_dword %0, %1, off sc0 sc1" :: "v"(fslot), "v"(tv) : "memory");
    }
    // ---- off-critical-path: out1 stores + x prefetch for t+1 ----
    o1a[0] = hn0;
    o1b[0] = hn1;
    o1a += NH;
    o1b += NH;
    {
      const int tx = (t + 1 < NT) ? (t + 1) : (NT - 1);
      const float* xs = xp0 + (size_t)tx * ND;
      asm volatile("global_load_dwordx4 %0, %1, off" : "=v"(xq0) : "v"(xs) : "memory");
      asm volatile("global_load_dwordx4 %0, %1, off offset:16" : "=v"(xq1) : "v"(xs) : "memory");
      asm volatile("global_load_dwordx4 %0, %1, off offset:128" : "=v"(xq2) : "v"(xs) : "memory");
      asm volatile("global_load_dwordx4 %0, %1, off offset:144" : "=v"(xq3) : "v"(xs) : "memory");
    }
  }
}

// ---------------------------------------------------------------------------
extern "C" void kernel_launch(void* const* d_in, const int* in_sizes, int n_in,
                              void* d_out, int out_size, void* d_ws, size_t ws_size,
                              hipStream_t stream) {
  (void)in_sizes; (void)n_in; (void)out_size; (void)ws_size;
  const float* in     = (const float*)d_in[0];
  const float* W_ih   = (const float*)d_in[1];
  const float* W_hh   = (const float*)d_in[2];
  const float* b_ih   = (const float*)d_in[3];
  const float* b_hh   = (const float*)d_in[4];
  const float* attn_W = (const float*)d_in[5];
  // d_in[6] (attn_b) cancels in the softmax -> unused.

  float* out0 = (float*)d_out;                          // (512,128,128)
  float* out1 = out0 + (size_t)NB * NT * ND;            // (512,128,512)

  float* attn_ws = (float*)d_ws;                                     // 256 KB
  unsigned short* hbuf = (unsigned short*)((char*)d_ws + 262144);    // 1 MB
  unsigned int* flags = (unsigned int*)((char*)d_ws + 262144 + 1048576); // 16 KB

  hipMemsetAsync(flags, 0, 16384, stream);
  attn_kernel<<<NB, 128, 0, stream>>>(in, attn_W, out0, attn_ws);
  rec_kernel<<<256, 512, 0, stream>>>(in, W_ih, W_hh, b_ih, b_hh, attn_ws,
                                      hbuf, flags, out1);
}